// Round 9
// baseline (139.252 us; speedup 1.0000x reference)
//
#include <hip/hip_runtime.h>
#include <math.h>

#define NN 50000
#define NE 800000
#define DF 128
#define NC 16
#define NBLK 200   // scan blocks
#define CHUNK 250  // elements per scan block (NBLK*CHUNK == NN)
#define WLD 136    // padded LDS row stride (bf16 elems)
#define NREP 8     // replicated degree counters (cuts atomic chain depth 8x)

typedef __bf16 bf16x8 __attribute__((ext_vector_type(8)));
typedef __bf16 bf16x4 __attribute__((ext_vector_type(4)));
typedef float  f32x4  __attribute__((ext_vector_type(4)));

#define GB ((NN + 63) / 64)    // gemm1 blocks in fused kernel (782)
#define DB ((NE + 511) / 512)  // deg/slot blocks (2 edges/thread) (1563)

// ---------------- prep: degi[8][NN]=0  +  W1->W1T bf16, W2->W2T bf16 --------
__global__ void k_prep(int* __restrict__ degi,
                       const float* __restrict__ W1, const float* __restrict__ W2,
                       __bf16* __restrict__ W1T, __bf16* __restrict__ W2T) {
    int i = blockIdx.x * blockDim.x + threadIdx.x;
    if (i < NN) {
#pragma unroll
        for (int r = 0; r < NREP; ++r) degi[r * NN + i] = 0;
    }
    int j = i - NN;
    if (j >= 0 && j < DF * DF) {
        int n = j >> 7, k = j & 127;
        W1T[j] = (__bf16)W1[k * DF + n];
    }
    int jj = j - DF * DF;
    if (jj >= 0 && jj < NC * DF) {
        int n = jj >> 7, k = jj & 127;
        W2T[jj] = (__bf16)W2[k * NC + n];
    }
}

// ---------------- fused: [0,GB) gemm1 (MFMA, LDS W) | deg+slot (replicated) -
// deg: replica r = (e>>9)&7 (constant per block -> replica stays on one XCD)
__global__ __launch_bounds__(256) void k_gemm1_deg(const float* __restrict__ X,
                                                   const __bf16* __restrict__ W1T,
                                                   __bf16* __restrict__ H1,
                                                   const int* __restrict__ dst,
                                                   int* __restrict__ degi,
                                                   int* __restrict__ slot) {
    __shared__ __bf16 wlds[DF * WLD];   // 34 KB
    if (blockIdx.x >= GB) {
        const int bb = blockIdx.x - GB;
        int* cnt = degi + (size_t)(bb & (NREP - 1)) * NN;
        int e0 = bb * 512 + threadIdx.x;
        int e1 = e0 + 256;
        int d0 = (e0 < NE) ? dst[e0] : 0;
        int d1 = (e1 < NE) ? dst[e1] : 0;
        if (e0 < NE) slot[e0] = atomicAdd(&cnt[d0], 1);
        if (e1 < NE) slot[e1] = atomicAdd(&cnt[d1], 1);
        return;
    }
    const int wid = threadIdx.x >> 6, lane = threadIdx.x & 63;
    const int m0 = blockIdx.x * 64 + wid * 16;
    const int m = m0 + (lane & 15);
    const int mc = (m < NN) ? m : NN - 1;       // clamped load row
    const int l15 = lane & 15;
    const int kb = (lane >> 4) * 8;             // k-chunk within 32-slice

    float4 xf[8];
#pragma unroll
    for (int q = 0; q < 4; ++q) {
        xf[2 * q]     = *(const float4*)&X[(size_t)mc * DF + q * 32 + kb];
        xf[2 * q + 1] = *(const float4*)&X[(size_t)mc * DF + q * 32 + kb + 4];
    }

    for (int i = threadIdx.x; i < DF * 16; i += 256) {
        int row = i >> 4, c8 = i & 15;
        *(bf16x8*)&wlds[row * WLD + c8 * 8] = ((const bf16x8*)W1T)[i];
    }
    __syncthreads();

    f32x4 acc[8];
#pragma unroll
    for (int nf = 0; nf < 8; ++nf) acc[nf] = (f32x4){0.f, 0.f, 0.f, 0.f};

#pragma unroll
    for (int ks = 0; ks < 4; ++ks) {
        float4 x0 = xf[2 * ks], x1 = xf[2 * ks + 1];
        bf16x8 xa;
        xa[0] = (__bf16)x0.x; xa[1] = (__bf16)x0.y; xa[2] = (__bf16)x0.z; xa[3] = (__bf16)x0.w;
        xa[4] = (__bf16)x1.x; xa[5] = (__bf16)x1.y; xa[6] = (__bf16)x1.z; xa[7] = (__bf16)x1.w;
#pragma unroll
        for (int nf = 0; nf < 8; ++nf) {
            bf16x8 wa = *(const bf16x8*)&wlds[(nf * 16 + l15) * WLD + ks * 32 + kb];
            acc[nf] = __builtin_amdgcn_mfma_f32_16x16x32_bf16(wa, xa, acc[nf], 0, 0, 0);
        }
    }
    if (m < NN) {
#pragma unroll
        for (int nf = 0; nf < 8; ++nf) {
            bf16x4 o;
            o[0] = (__bf16)acc[nf][0]; o[1] = (__bf16)acc[nf][1];
            o[2] = (__bf16)acc[nf][2]; o[3] = (__bf16)acc[nf][3];
            *(bf16x4*)&H1[(size_t)m * DF + nf * 16 + (lane >> 4) * 4] = o;
        }
    }
}

// ---------------- phase 1: per-block partial sums over all replicas ---------
__global__ __launch_bounds__(256) void k_part(const int* __restrict__ degi,
                                              int* __restrict__ part) {
    __shared__ int ws[4];
    const int b = blockIdx.x, t = threadIdx.x;
    int s = 0;
    if (t < CHUNK) {
        const int idx = b * CHUNK + t;
#pragma unroll
        for (int r = 0; r < NREP; ++r) s += degi[r * NN + idx];
    }
    for (int o = 32; o > 0; o >>= 1) s += __shfl_down(s, o);
    if ((t & 63) == 0) ws[t >> 6] = s;
    __syncthreads();
    if (t == 0) part[b] = ws[0] + ws[1] + ws[2] + ws[3];
}

// ---------------- phase 2: scan the NBLK partials ----------------
__global__ __launch_bounds__(256) void k_scan_part(const int* __restrict__ part,
                                                   int* __restrict__ partoff,
                                                   int* __restrict__ off) {
    __shared__ int s[256];
    const int t = threadIdx.x;
    int v = (t < NBLK) ? part[t] : 0;
    s[t] = v;
    __syncthreads();
    for (int o = 1; o < 256; o <<= 1) {
        int x = (t >= o) ? s[t - o] : 0;
        __syncthreads();
        s[t] += x;
        __syncthreads();
    }
    if (t < NBLK) partoff[t] = s[t] - v;
    if (t == 255) off[NN] = s[255];
}

// ---------------- phase 3: offsets + per-replica bases + dis ----------------
__global__ __launch_bounds__(256) void k_off(const int* __restrict__ degi,
                                             const int* __restrict__ partoff,
                                             int* __restrict__ off,
                                             int* __restrict__ base,
                                             float* __restrict__ dis) {
    __shared__ int s[256];
    const int b = blockIdx.x, t = threadIdx.x;
    const int idx = b * CHUNK + t;
    int c[NREP];
    int v = 0;
    if (t < CHUNK) {
#pragma unroll
        for (int r = 0; r < NREP; ++r) { c[r] = degi[r * NN + idx]; v += c[r]; }
    }
    s[t] = v;
    __syncthreads();
    for (int o = 1; o < 256; o <<= 1) {
        int x = (t >= o) ? s[t - o] : 0;
        __syncthreads();
        s[t] += x;
        __syncthreads();
    }
    if (t < CHUNK) {
        int o0 = partoff[b] + s[t] - v;        // exclusive prefix = off[idx]
        off[idx] = o0;
        int run = o0;
#pragma unroll
        for (int r = 0; r < NREP; ++r) { base[r * NN + idx] = run; run += c[r]; }
        dis[idx] = rsqrtf((float)(v + 1));     // +1 self-loop
    }
}

// ---------------- CSR fill (atomic-free): rec[base[r][d]+slot[e]] -----------
__global__ void k_csr_fill(const int* __restrict__ src, const int* __restrict__ dst,
                           const int* __restrict__ slot,
                           const float* __restrict__ dis, const int* __restrict__ base,
                           int2* __restrict__ rec) {
    int e = (blockIdx.x * blockDim.x + threadIdx.x) * 2;
#pragma unroll
    for (int u = 0; u < 2; ++u, ++e) {
        if (e < NE) {
            int s = src[e], d = dst[e];
            int r = (e >> 9) & (NREP - 1);
            float w = dis[s] * dis[d];
            rec[base[r * NN + d] + slot[e]] = make_int2(s, __float_as_int(w));
        }
    }
}

// ---------------- agg1 + gemm2 fused: one node per wave ---------------------
__global__ __launch_bounds__(256) void k_agg1g2(const __bf16* __restrict__ H1,
                                                const float* __restrict__ dis,
                                                const float* __restrict__ b1,
                                                const __bf16* __restrict__ W2T,
                                                const int* __restrict__ off,
                                                const int2* __restrict__ rec,
                                                float* __restrict__ H2) {
    const int wid = threadIdx.x >> 6, lane = threadIdx.x & 63;
    const int n = blockIdx.x * 4 + wid;
    if (n >= NN) return;
    const int g = lane >> 4, l16 = lane & 15;
    const int fo = l16 * 8;

    float a[8];
    if (g == 0) {
        float dn = dis[n], d2 = dn * dn;
        float4 b0 = *(const float4*)&b1[fo];
        float4 b4 = *(const float4*)&b1[fo + 4];
        bf16x8 hs = *(const bf16x8*)&H1[(size_t)n * DF + fo];
        a[0] = b0.x + (float)hs[0] * d2;
        a[1] = b0.y + (float)hs[1] * d2;
        a[2] = b0.z + (float)hs[2] * d2;
        a[3] = b0.w + (float)hs[3] * d2;
        a[4] = b4.x + (float)hs[4] * d2;
        a[5] = b4.y + (float)hs[5] * d2;
        a[6] = b4.z + (float)hs[6] * d2;
        a[7] = b4.w + (float)hs[7] * d2;
    } else {
#pragma unroll
        for (int i = 0; i < 8; ++i) a[i] = 0.f;
    }

    const int e0 = off[n], e1 = off[n + 1];
    int e = e0 + g;
    for (; e + 4 < e1; e += 8) {
        int2 r0 = rec[e];
        int2 r1 = rec[e + 4];
        float w0 = __int_as_float(r0.y);
        float w1 = __int_as_float(r1.y);
        bf16x8 h0 = *(const bf16x8*)&H1[(size_t)r0.x * DF + fo];
        bf16x8 h1 = *(const bf16x8*)&H1[(size_t)r1.x * DF + fo];
#pragma unroll
        for (int i = 0; i < 8; ++i) a[i] += (float)h0[i] * w0;
#pragma unroll
        for (int i = 0; i < 8; ++i) a[i] += (float)h1[i] * w1;
    }
    for (; e < e1; e += 4) {
        int2 r = rec[e];
        float w = __int_as_float(r.y);
        bf16x8 h = *(const bf16x8*)&H1[(size_t)r.x * DF + fo];
#pragma unroll
        for (int i = 0; i < 8; ++i) a[i] += (float)h[i] * w;
    }
#pragma unroll
    for (int i = 0; i < 8; ++i) {
        a[i] += __shfl_xor(a[i], 16);
        a[i] += __shfl_xor(a[i], 32);
        a[i] = fmaxf(a[i], 0.f);               // ReLU (all lanes hold full row)
    }

    // mini-GEMM: lane computes 4 classes (g*4..g*4+3) over its 8 feats
    float p[4];
#pragma unroll
    for (int j = 0; j < 4; ++j) {
        bf16x8 wr = *(const bf16x8*)&W2T[(size_t)(g * 4 + j) * DF + fo];
        float s = 0.f;
#pragma unroll
        for (int i = 0; i < 8; ++i) s += a[i] * (float)wr[i];
        p[j] = s;
    }
#pragma unroll
    for (int o = 1; o <= 8; o <<= 1) {
#pragma unroll
        for (int j = 0; j < 4; ++j) p[j] += __shfl_xor(p[j], o);
    }
    if (l16 == 0) {
        f32x4 o4 = {p[0], p[1], p[2], p[3]};
        *(f32x4*)&H2[(size_t)n * NC + g * 4] = o4;
    }
}

// ---------------- agg layer 2: 8 edges in flight, fused sigmoid -> OUT ------
__global__ __launch_bounds__(256) void k_agg2(const float* __restrict__ H2,
                                              const float* __restrict__ dis,
                                              const float* __restrict__ b2,
                                              const int* __restrict__ off,
                                              const int2* __restrict__ rec,
                                              float* __restrict__ OUT) {
    const int wid = threadIdx.x >> 6, lane = threadIdx.x & 63;
    const int n = blockIdx.x * 4 + wid;
    if (n >= NN) return;

    const int g = lane >> 3, l8 = lane & 7;
    float ax = 0.f, ay = 0.f;
    const int e0 = off[n], e1 = off[n + 1];
    for (int e = e0 + g; e < e1; e += 8) {
        int2 r = rec[e];
        float w = __int_as_float(r.y);
        float2 h = *(const float2*)&H2[(size_t)r.x * NC + l8 * 2];
        ax += h.x * w;
        ay += h.y * w;
    }
    ax += __shfl_xor(ax, 8);  ay += __shfl_xor(ay, 8);
    ax += __shfl_xor(ax, 16); ay += __shfl_xor(ay, 16);
    ax += __shfl_xor(ax, 32); ay += __shfl_xor(ay, 32);
    if (g == 0) {
        float dn = dis[n], d2 = dn * dn;
        float2 hs = *(const float2*)&H2[(size_t)n * NC + l8 * 2];
        float2 bb = *(const float2*)&b2[l8 * 2];
        float vx = bb.x + hs.x * d2 + ax;
        float vy = bb.y + hs.y * d2 + ay;
        float2 o = { 1.0f / (1.0f + expf(-vx)), 1.0f / (1.0f + expf(-vy)) };
        *(float2*)&OUT[(size_t)n * NC + l8 * 2] = o;
    }
}

extern "C" void kernel_launch(void* const* d_in, const int* in_sizes, int n_in,
                              void* d_out, int out_size, void* d_ws, size_t ws_size,
                              hipStream_t stream) {
    const float* X  = (const float*)d_in[0];
    const int*   EI = (const int*)d_in[1];
    const float* W1 = (const float*)d_in[2];
    const float* b1 = (const float*)d_in[3];
    const float* W2 = (const float*)d_in[4];
    const float* b2 = (const float*)d_in[5];
    float* OUT = (float*)d_out;

    const int* src = EI;
    const int* dst = EI + NE;

    // workspace layout (bytes)
    char* ws = (char*)d_ws;
    int*    degi    = (int*)(ws);                   // NREP*NN ints = 1.6 MB
    int*    off     = (int*)(ws + 1638400);         // NN+1
    int*    part    = (int*)(ws + 1900544);         // NBLK
    int*    partoff = (int*)(ws + 1904640);         // NBLK
    float*  dis     = (float*)(ws + 1908736);       // NN
    __bf16* W1T     = (__bf16*)(ws + 2162688);      // 128*128 bf16 = 32 KB
    __bf16* W2T     = (__bf16*)(ws + 2195456);      // 16*128 bf16 = 4 KB
    int*    base    = (int*)(ws + 2199552);         // NREP*NN ints = 1.6 MB
    int*    slot    = (int*)(ws + 3837952);         // NE ints = 3.2 MB
    int2*   rec     = (int2*)(ws + 7077888);        // NE int2 = 6.4 MB
    __bf16* H1      = (__bf16*)(ws + 13893632);     // NN*DF bf16 = 12.8 MB
    float*  H2      = (float*)(ws + 26693632);      // NN*NC f32 = 3.2 MB

    const int B = 256;

    k_prep<<<(NN + DF * DF + NC * DF + B - 1) / B, B, 0, stream>>>(degi, W1, W2, W1T, W2T);
    k_gemm1_deg<<<GB + DB, B, 0, stream>>>(X, W1T, H1, dst, degi, slot);
    k_part<<<NBLK, B, 0, stream>>>(degi, part);
    k_scan_part<<<1, B, 0, stream>>>(part, partoff, off);
    k_off<<<NBLK, B, 0, stream>>>(degi, partoff, off, base, dis);
    k_csr_fill<<<(NE / 2 + B - 1) / B, B, 0, stream>>>(src, dst, slot, dis, base, rec);

    k_agg1g2<<<(NN + 3) / 4, B, 0, stream>>>(H1, dis, b1, W2T, off, rec, H2);
    k_agg2<<<(NN + 3) / 4, B, 0, stream>>>(H2, dis, b2, off, rec, OUT);
}

// Round 10
// 110.321 us; speedup vs baseline: 1.2622x; 1.2622x over previous
//
#include <hip/hip_runtime.h>
#include <math.h>

#define NN 50000
#define NE 800000
#define DF 128
#define NC 16
#define WLD 136            // padded LDS row stride (bf16 elems)
#define NBIN 196           // buckets: bin = dst>>8 (256 nodes per bucket)
#define EPB 2048           // edges per hist/scatter block
#define HB ((NE + EPB - 1) / EPB)      // 391 hist blocks
#define HL (NBIN * HB)                 // 76636 h entries
#define PB ((HL + 255) / 256)          // 300 scan blocks
#define GB ((NN + 63) / 64)            // 782 gemm1 blocks

typedef __bf16 bf16x8 __attribute__((ext_vector_type(8)));
typedef __bf16 bf16x4 __attribute__((ext_vector_type(4)));
typedef float  f32x4  __attribute__((ext_vector_type(4)));

// ---------------- prep: W1->W1T bf16 [128][128], W2->W2T bf16 [16][128] -----
__global__ void k_prep(const float* __restrict__ W1, const float* __restrict__ W2,
                       __bf16* __restrict__ W1T, __bf16* __restrict__ W2T) {
    int i = blockIdx.x * blockDim.x + threadIdx.x;
    if (i < DF * DF) {
        int n = i >> 7, k = i & 127;
        W1T[i] = (__bf16)W1[k * DF + n];
    }
    int j = i - DF * DF;
    if (j >= 0 && j < NC * DF) {
        int n = j >> 7, k = j & 127;
        W2T[j] = (__bf16)W2[k * NC + n];
    }
}

// ---------------- fused: [0,GB) gemm1 (MFMA, LDS W) | [GB,GB+HB) histogram --
__global__ __launch_bounds__(256) void k_gemm1_hist(const float* __restrict__ X,
                                                    const __bf16* __restrict__ W1T,
                                                    __bf16* __restrict__ H1,
                                                    const int* __restrict__ dst,
                                                    int* __restrict__ h) {
    __shared__ __bf16 wlds[DF * WLD];   // 34 KB
    __shared__ int hc[NBIN];
    if (blockIdx.x >= GB) {
        const int bb = blockIdx.x - GB;
        const int t = threadIdx.x;
        if (t < NBIN) hc[t] = 0;
        __syncthreads();
        const int base = bb * EPB;
#pragma unroll
        for (int i = 0; i < EPB / 256; ++i) {
            int e = base + i * 256 + t;
            if (e < NE) atomicAdd(&hc[dst[e] >> 8], 1);
        }
        __syncthreads();
        if (t < NBIN) h[t * HB + bb] = hc[t];   // bin-major
        return;
    }
    const int wid = threadIdx.x >> 6, lane = threadIdx.x & 63;
    const int m0 = blockIdx.x * 64 + wid * 16;
    const int m = m0 + (lane & 15);
    const int mc = (m < NN) ? m : NN - 1;
    const int l15 = lane & 15;
    const int kb = (lane >> 4) * 8;

    float4 xf[8];
#pragma unroll
    for (int q = 0; q < 4; ++q) {
        xf[2 * q]     = *(const float4*)&X[(size_t)mc * DF + q * 32 + kb];
        xf[2 * q + 1] = *(const float4*)&X[(size_t)mc * DF + q * 32 + kb + 4];
    }
    for (int i = threadIdx.x; i < DF * 16; i += 256) {
        int row = i >> 4, c8 = i & 15;
        *(bf16x8*)&wlds[row * WLD + c8 * 8] = ((const bf16x8*)W1T)[i];
    }
    __syncthreads();

    f32x4 acc[8];
#pragma unroll
    for (int nf = 0; nf < 8; ++nf) acc[nf] = (f32x4){0.f, 0.f, 0.f, 0.f};
#pragma unroll
    for (int ks = 0; ks < 4; ++ks) {
        float4 x0 = xf[2 * ks], x1 = xf[2 * ks + 1];
        bf16x8 xa;
        xa[0] = (__bf16)x0.x; xa[1] = (__bf16)x0.y; xa[2] = (__bf16)x0.z; xa[3] = (__bf16)x0.w;
        xa[4] = (__bf16)x1.x; xa[5] = (__bf16)x1.y; xa[6] = (__bf16)x1.z; xa[7] = (__bf16)x1.w;
#pragma unroll
        for (int nf = 0; nf < 8; ++nf) {
            bf16x8 wa = *(const bf16x8*)&wlds[(nf * 16 + l15) * WLD + ks * 32 + kb];
            acc[nf] = __builtin_amdgcn_mfma_f32_16x16x32_bf16(wa, xa, acc[nf], 0, 0, 0);
        }
    }
    if (m < NN) {
#pragma unroll
        for (int nf = 0; nf < 8; ++nf) {
            bf16x4 o;
            o[0] = (__bf16)acc[nf][0]; o[1] = (__bf16)acc[nf][1];
            o[2] = (__bf16)acc[nf][2]; o[3] = (__bf16)acc[nf][3];
            *(bf16x4*)&H1[(size_t)m * DF + nf * 16 + (lane >> 4) * 4] = o;
        }
    }
}

// ---------------- scan phase 1: per-block partial sums of h ----------------
__global__ __launch_bounds__(256) void k_hpart(const int* __restrict__ h,
                                               int* __restrict__ part) {
    __shared__ int ws[4];
    const int b = blockIdx.x, t = threadIdx.x;
    const int idx = b * 256 + t;
    int s = (idx < HL) ? h[idx] : 0;
    for (int o = 32; o > 0; o >>= 1) s += __shfl_down(s, o);
    if ((t & 63) == 0) ws[t >> 6] = s;
    __syncthreads();
    if (t == 0) part[b] = ws[0] + ws[1] + ws[2] + ws[3];
}

// ---------------- scan phase 2: scan PB partials (single 512-block) ---------
__global__ __launch_bounds__(512) void k_hscan_part(const int* __restrict__ part,
                                                    int* __restrict__ partoff,
                                                    int* __restrict__ hscan) {
    __shared__ int s[512];
    const int t = threadIdx.x;
    int v = (t < PB) ? part[t] : 0;
    s[t] = v;
    __syncthreads();
    for (int o = 1; o < 512; o <<= 1) {
        int x = (t >= o) ? s[t - o] : 0;
        __syncthreads();
        s[t] += x;
        __syncthreads();
    }
    if (t < PB) partoff[t] = s[t] - v;       // exclusive
    if (t == 511) hscan[HL] = s[511];        // sentinel = NE
}

// ---------------- scan phase 3: block-local scan -> hscan -------------------
__global__ __launch_bounds__(256) void k_hoff(const int* __restrict__ h,
                                              const int* __restrict__ partoff,
                                              int* __restrict__ hscan) {
    __shared__ int s[256];
    const int b = blockIdx.x, t = threadIdx.x;
    const int idx = b * 256 + t;
    int v = (idx < HL) ? h[idx] : 0;
    s[t] = v;
    __syncthreads();
    for (int o = 1; o < 256; o <<= 1) {
        int x = (t >= o) ? s[t - o] : 0;
        __syncthreads();
        s[t] += x;
        __syncthreads();
    }
    if (idx < HL) hscan[idx] = partoff[b] + s[t] - v;
}

// ---------------- scatter into buckets (LDS cursors, no global atomics) -----
__global__ __launch_bounds__(256) void k_scatterA(const int* __restrict__ src,
                                                  const int* __restrict__ dst,
                                                  const int* __restrict__ hscan,
                                                  int2* __restrict__ ebuf) {
    __shared__ int cur[NBIN];
    const int bb = blockIdx.x, t = threadIdx.x;
    if (t < NBIN) cur[t] = hscan[t * HB + bb];
    __syncthreads();
    const int base = bb * EPB;
#pragma unroll
    for (int i = 0; i < EPB / 256; ++i) {
        int e = base + i * 256 + t;
        if (e < NE) {
            int s = src[e], d = dst[e];
            int pos = atomicAdd(&cur[d >> 8], 1);
            ebuf[pos] = make_int2(s, d);
        }
    }
}

// ---------------- per-bucket rank: off, dis, rec[src] -----------------------
__global__ __launch_bounds__(256) void k_rankB(const int2* __restrict__ ebuf,
                                               const int* __restrict__ hscan,
                                               int* __restrict__ off,
                                               float* __restrict__ dis,
                                               int* __restrict__ rec) {
    __shared__ int cnt[256], s[256], cur[256];
    const int bin = blockIdx.x, t = threadIdx.x;
    const int base = hscan[bin * HB];
    const int end  = hscan[(bin + 1) * HB];   // bin+1==NBIN -> sentinel = NE
    cnt[t] = 0;
    __syncthreads();
    for (int e = base + t; e < end; e += 256)
        atomicAdd(&cnt[ebuf[e].y & 255], 1);
    __syncthreads();
    int c = cnt[t];
    s[t] = c;
    __syncthreads();
    for (int o = 1; o < 256; o <<= 1) {
        int x = (t >= o) ? s[t - o] : 0;
        __syncthreads();
        s[t] += x;
        __syncthreads();
    }
    int lo = s[t] - c;                         // exclusive within bucket
    int d = (bin << 8) + t;
    if (d < NN) {
        off[d] = base + lo;
        dis[d] = rsqrtf((float)(c + 1));       // +1 self-loop
    }
    if (bin == NBIN - 1 && t == 0) off[NN] = NE;
    cur[t] = base + lo;
    __syncthreads();
    for (int e = base + t; e < end; e += 256) {
        int2 ed = ebuf[e];
        int p = atomicAdd(&cur[ed.y & 255], 1);
        rec[p] = ed.x;
    }
}

// ---------------- agg1 + gemm2 fused: one node per wave ---------------------
__global__ __launch_bounds__(256) void k_agg1g2(const __bf16* __restrict__ H1,
                                                const float* __restrict__ dis,
                                                const float* __restrict__ b1,
                                                const __bf16* __restrict__ W2T,
                                                const int* __restrict__ off,
                                                const int* __restrict__ rec,
                                                float* __restrict__ H2) {
    const int wid = threadIdx.x >> 6, lane = threadIdx.x & 63;
    const int n = blockIdx.x * 4 + wid;
    if (n >= NN) return;
    const int g = lane >> 4, l16 = lane & 15;
    const int fo = l16 * 8;
    const float dn = dis[n];

    float a[8];
    if (g == 0) {
        float d2 = dn * dn;
        float4 b0 = *(const float4*)&b1[fo];
        float4 b4 = *(const float4*)&b1[fo + 4];
        bf16x8 hs = *(const bf16x8*)&H1[(size_t)n * DF + fo];
        a[0] = b0.x + (float)hs[0] * d2;
        a[1] = b0.y + (float)hs[1] * d2;
        a[2] = b0.z + (float)hs[2] * d2;
        a[3] = b0.w + (float)hs[3] * d2;
        a[4] = b4.x + (float)hs[4] * d2;
        a[5] = b4.y + (float)hs[5] * d2;
        a[6] = b4.z + (float)hs[6] * d2;
        a[7] = b4.w + (float)hs[7] * d2;
    } else {
#pragma unroll
        for (int i = 0; i < 8; ++i) a[i] = 0.f;
    }

    const int e0 = off[n], e1 = off[n + 1];
    int e = e0 + g;
    for (; e + 4 < e1; e += 8) {
        int r0 = rec[e];
        int r1 = rec[e + 4];
        float w0 = dis[r0] * dn;
        float w1 = dis[r1] * dn;
        bf16x8 h0 = *(const bf16x8*)&H1[(size_t)r0 * DF + fo];
        bf16x8 h1 = *(const bf16x8*)&H1[(size_t)r1 * DF + fo];
#pragma unroll
        for (int i = 0; i < 8; ++i) a[i] += (float)h0[i] * w0;
#pragma unroll
        for (int i = 0; i < 8; ++i) a[i] += (float)h1[i] * w1;
    }
    for (; e < e1; e += 4) {
        int r = rec[e];
        float w = dis[r] * dn;
        bf16x8 h = *(const bf16x8*)&H1[(size_t)r * DF + fo];
#pragma unroll
        for (int i = 0; i < 8; ++i) a[i] += (float)h[i] * w;
    }
#pragma unroll
    for (int i = 0; i < 8; ++i) {
        a[i] += __shfl_xor(a[i], 16);
        a[i] += __shfl_xor(a[i], 32);
        a[i] = fmaxf(a[i], 0.f);               // ReLU (all lanes hold full row)
    }

    // mini-GEMM: lane computes 4 classes (g*4..g*4+3) over its 8 feats
    float p[4];
#pragma unroll
    for (int j = 0; j < 4; ++j) {
        bf16x8 wr = *(const bf16x8*)&W2T[(size_t)(g * 4 + j) * DF + fo];
        float s = 0.f;
#pragma unroll
        for (int i = 0; i < 8; ++i) s += a[i] * (float)wr[i];
        p[j] = s;
    }
#pragma unroll
    for (int o = 1; o <= 8; o <<= 1) {
#pragma unroll
        for (int j = 0; j < 4; ++j) p[j] += __shfl_xor(p[j], o);
    }
    if (l16 == 0) {
        f32x4 o4 = {p[0], p[1], p[2], p[3]};
        *(f32x4*)&H2[(size_t)n * NC + g * 4] = o4;
    }
}

// ---------------- agg layer 2: 8 edges in flight, fused sigmoid -> OUT ------
__global__ __launch_bounds__(256) void k_agg2(const float* __restrict__ H2,
                                              const float* __restrict__ dis,
                                              const float* __restrict__ b2,
                                              const int* __restrict__ off,
                                              const int* __restrict__ rec,
                                              float* __restrict__ OUT) {
    const int wid = threadIdx.x >> 6, lane = threadIdx.x & 63;
    const int n = blockIdx.x * 4 + wid;
    if (n >= NN) return;
    const float dn = dis[n];

    const int g = lane >> 3, l8 = lane & 7;
    float ax = 0.f, ay = 0.f;
    const int e0 = off[n], e1 = off[n + 1];
    for (int e = e0 + g; e < e1; e += 8) {
        int r = rec[e];
        float w = dis[r] * dn;
        float2 h = *(const float2*)&H2[(size_t)r * NC + l8 * 2];
        ax += h.x * w;
        ay += h.y * w;
    }
    ax += __shfl_xor(ax, 8);  ay += __shfl_xor(ay, 8);
    ax += __shfl_xor(ax, 16); ay += __shfl_xor(ay, 16);
    ax += __shfl_xor(ax, 32); ay += __shfl_xor(ay, 32);
    if (g == 0) {
        float d2 = dn * dn;
        float2 hs = *(const float2*)&H2[(size_t)n * NC + l8 * 2];
        float2 bb = *(const float2*)&b2[l8 * 2];
        float vx = bb.x + hs.x * d2 + ax;
        float vy = bb.y + hs.y * d2 + ay;
        float2 o = { 1.0f / (1.0f + expf(-vx)), 1.0f / (1.0f + expf(-vy)) };
        *(float2*)&OUT[(size_t)n * NC + l8 * 2] = o;
    }
}

extern "C" void kernel_launch(void* const* d_in, const int* in_sizes, int n_in,
                              void* d_out, int out_size, void* d_ws, size_t ws_size,
                              hipStream_t stream) {
    const float* X  = (const float*)d_in[0];
    const int*   EI = (const int*)d_in[1];
    const float* W1 = (const float*)d_in[2];
    const float* b1 = (const float*)d_in[3];
    const float* W2 = (const float*)d_in[4];
    const float* b2 = (const float*)d_in[5];
    float* OUT = (float*)d_out;

    const int* src = EI;
    const int* dst = EI + NE;

    // workspace layout (bytes)
    char* ws = (char*)d_ws;
    int*    h       = (int*)(ws);                   // HL ints        = 306.5 KB
    int*    hscan   = (int*)(ws + 327680);          // HL+1 ints      = 306.5 KB
    int*    hpart   = (int*)(ws + 655360);          // PB ints
    int*    hpartoff= (int*)(ws + 659456);          // PB ints
    int*    off     = (int*)(ws + 663552);          // NN+1 ints
    float*  dis     = (float*)(ws + 868352);        // NN floats
    __bf16* W1T     = (__bf16*)(ws + 1073152);      // 32 KB
    __bf16* W2T     = (__bf16*)(ws + 1105920);      // 4 KB
    int2*   ebuf    = (int2*)(ws + 1110016);        // NE int2 = 6.4 MB
    int*    rec     = (int*)(ws + 7510016);         // NE int  = 3.2 MB
    __bf16* H1      = (__bf16*)(ws + 10710016);     // NN*DF bf16 = 12.8 MB
    float*  H2      = (float*)(ws + 23510016);      // NN*NC f32 = 3.2 MB

    const int B = 256;

    k_prep<<<(DF * DF + NC * DF + B - 1) / B, B, 0, stream>>>(W1, W2, W1T, W2T);
    k_gemm1_hist<<<GB + HB, B, 0, stream>>>(X, W1T, H1, dst, h);
    k_hpart<<<PB, B, 0, stream>>>(h, hpart);
    k_hscan_part<<<1, 512, 0, stream>>>(hpart, hpartoff, hscan);
    k_hoff<<<PB, B, 0, stream>>>(h, hpartoff, hscan);
    k_scatterA<<<HB, B, 0, stream>>>(src, dst, hscan, ebuf);
    k_rankB<<<NBIN, B, 0, stream>>>(ebuf, hscan, off, dis, rec);

    k_agg1g2<<<(NN + 3) / 4, B, 0, stream>>>(H1, dis, b1, W2T, off, rec, H2);
    k_agg2<<<(NN + 3) / 4, B, 0, stream>>>(H2, dis, b2, off, rec, OUT);
}

// Round 11
// 104.533 us; speedup vs baseline: 1.3321x; 1.0554x over previous
//
#include <hip/hip_runtime.h>
#include <math.h>

#define NN 50000
#define NE 800000
#define DF 128
#define NC 16
#define WLD 136            // padded LDS row stride (bf16 elems)
#define NBIN 196           // buckets: bin = dst>>8 (256 nodes per bucket)
#define EPB 2048           // edges per hist/scatter block
#define HB ((NE + EPB - 1) / EPB)      // 391 hist blocks
#define HL (NBIN * HB)                 // 76636 h entries
#define PB ((HL + 255) / 256)          // 300 scan blocks
#define GB ((NN + 63) / 64)            // 782 gemm1 blocks

typedef __bf16 bf16x8 __attribute__((ext_vector_type(8)));
typedef __bf16 bf16x4 __attribute__((ext_vector_type(4)));
typedef float  f32x4  __attribute__((ext_vector_type(4)));

// ---------------- prep: W1->W1T bf16 [128][128], W2->W2T bf16 [16][128] -----
__global__ void k_prep(const float* __restrict__ W1, const float* __restrict__ W2,
                       __bf16* __restrict__ W1T, __bf16* __restrict__ W2T) {
    int i = blockIdx.x * blockDim.x + threadIdx.x;
    if (i < DF * DF) {
        int n = i >> 7, k = i & 127;
        W1T[i] = (__bf16)W1[k * DF + n];
    }
    int j = i - DF * DF;
    if (j >= 0 && j < NC * DF) {
        int n = j >> 7, k = j & 127;
        W2T[j] = (__bf16)W2[k * NC + n];
    }
}

// ---------------- fused: [0,GB) gemm1 (MFMA, LDS W) | [GB,GB+HB) histogram --
__global__ __launch_bounds__(256) void k_gemm1_hist(const float* __restrict__ X,
                                                    const __bf16* __restrict__ W1T,
                                                    __bf16* __restrict__ H1,
                                                    const int* __restrict__ dst,
                                                    int* __restrict__ h) {
    __shared__ __bf16 wlds[DF * WLD];   // 34 KB
    __shared__ int hc[NBIN];
    if (blockIdx.x >= GB) {
        const int bb = blockIdx.x - GB;
        const int t = threadIdx.x;
        if (t < NBIN) hc[t] = 0;
        __syncthreads();
        const int base = bb * EPB;
#pragma unroll
        for (int i = 0; i < EPB / 256; ++i) {
            int e = base + i * 256 + t;
            if (e < NE) atomicAdd(&hc[dst[e] >> 8], 1);
        }
        __syncthreads();
        if (t < NBIN) h[t * HB + bb] = hc[t];   // bin-major
        return;
    }
    const int wid = threadIdx.x >> 6, lane = threadIdx.x & 63;
    const int m0 = blockIdx.x * 64 + wid * 16;
    const int m = m0 + (lane & 15);
    const int mc = (m < NN) ? m : NN - 1;
    const int l15 = lane & 15;
    const int kb = (lane >> 4) * 8;

    float4 xf[8];
#pragma unroll
    for (int q = 0; q < 4; ++q) {
        xf[2 * q]     = *(const float4*)&X[(size_t)mc * DF + q * 32 + kb];
        xf[2 * q + 1] = *(const float4*)&X[(size_t)mc * DF + q * 32 + kb + 4];
    }
    for (int i = threadIdx.x; i < DF * 16; i += 256) {
        int row = i >> 4, c8 = i & 15;
        *(bf16x8*)&wlds[row * WLD + c8 * 8] = ((const bf16x8*)W1T)[i];
    }
    __syncthreads();

    f32x4 acc[8];
#pragma unroll
    for (int nf = 0; nf < 8; ++nf) acc[nf] = (f32x4){0.f, 0.f, 0.f, 0.f};
#pragma unroll
    for (int ks = 0; ks < 4; ++ks) {
        float4 x0 = xf[2 * ks], x1 = xf[2 * ks + 1];
        bf16x8 xa;
        xa[0] = (__bf16)x0.x; xa[1] = (__bf16)x0.y; xa[2] = (__bf16)x0.z; xa[3] = (__bf16)x0.w;
        xa[4] = (__bf16)x1.x; xa[5] = (__bf16)x1.y; xa[6] = (__bf16)x1.z; xa[7] = (__bf16)x1.w;
#pragma unroll
        for (int nf = 0; nf < 8; ++nf) {
            bf16x8 wa = *(const bf16x8*)&wlds[(nf * 16 + l15) * WLD + ks * 32 + kb];
            acc[nf] = __builtin_amdgcn_mfma_f32_16x16x32_bf16(wa, xa, acc[nf], 0, 0, 0);
        }
    }
    if (m < NN) {
#pragma unroll
        for (int nf = 0; nf < 8; ++nf) {
            bf16x4 o;
            o[0] = (__bf16)acc[nf][0]; o[1] = (__bf16)acc[nf][1];
            o[2] = (__bf16)acc[nf][2]; o[3] = (__bf16)acc[nf][3];
            *(bf16x4*)&H1[(size_t)m * DF + nf * 16 + (lane >> 4) * 4] = o;
        }
    }
}

// ---------------- scan phase 1: per-block partial sums of h ----------------
__global__ __launch_bounds__(256) void k_hpart(const int* __restrict__ h,
                                               int* __restrict__ part) {
    __shared__ int ws[4];
    const int b = blockIdx.x, t = threadIdx.x;
    const int idx = b * 256 + t;
    int s = (idx < HL) ? h[idx] : 0;
    for (int o = 32; o > 0; o >>= 1) s += __shfl_down(s, o);
    if ((t & 63) == 0) ws[t >> 6] = s;
    __syncthreads();
    if (t == 0) part[b] = ws[0] + ws[1] + ws[2] + ws[3];
}

// ---------------- scan phase 2: scan PB partials (single 512-block) ---------
__global__ __launch_bounds__(512) void k_hscan_part(const int* __restrict__ part,
                                                    int* __restrict__ partoff,
                                                    int* __restrict__ hscan) {
    __shared__ int s[512];
    const int t = threadIdx.x;
    int v = (t < PB) ? part[t] : 0;
    s[t] = v;
    __syncthreads();
    for (int o = 1; o < 512; o <<= 1) {
        int x = (t >= o) ? s[t - o] : 0;
        __syncthreads();
        s[t] += x;
        __syncthreads();
    }
    if (t < PB) partoff[t] = s[t] - v;       // exclusive
    if (t == 511) hscan[HL] = s[511];        // sentinel = NE
}

// ---------------- scan phase 3: block-local scan -> hscan -------------------
__global__ __launch_bounds__(256) void k_hoff(const int* __restrict__ h,
                                              const int* __restrict__ partoff,
                                              int* __restrict__ hscan) {
    __shared__ int s[256];
    const int b = blockIdx.x, t = threadIdx.x;
    const int idx = b * 256 + t;
    int v = (idx < HL) ? h[idx] : 0;
    s[t] = v;
    __syncthreads();
    for (int o = 1; o < 256; o <<= 1) {
        int x = (t >= o) ? s[t - o] : 0;
        __syncthreads();
        s[t] += x;
        __syncthreads();
    }
    if (idx < HL) hscan[idx] = partoff[b] + s[t] - v;
}

// ---------------- scatter into buckets (packed: (dst&255)<<16 | src) --------
__global__ __launch_bounds__(256) void k_scatterA(const int* __restrict__ src,
                                                  const int* __restrict__ dst,
                                                  const int* __restrict__ hscan,
                                                  int* __restrict__ ebuf) {
    __shared__ int cur[NBIN];
    const int bb = blockIdx.x, t = threadIdx.x;
    if (t < NBIN) cur[t] = hscan[t * HB + bb];
    __syncthreads();
    const int base = bb * EPB;
#pragma unroll
    for (int i = 0; i < EPB / 256; ++i) {
        int e = base + i * 256 + t;
        if (e < NE) {
            int s = src[e], d = dst[e];
            int pos = atomicAdd(&cur[d >> 8], 1);
            ebuf[pos] = s | ((d & 255) << 16);
        }
    }
}

// ---------------- per-bucket rank: off, dis, rec[src] (ushort) --------------
__global__ __launch_bounds__(256) void k_rankB(const int* __restrict__ ebuf,
                                               const int* __restrict__ hscan,
                                               int* __restrict__ off,
                                               float* __restrict__ dis,
                                               unsigned short* __restrict__ rec) {
    __shared__ int cnt[256], s[256], cur[256];
    const int bin = blockIdx.x, t = threadIdx.x;
    const int base = hscan[bin * HB];
    const int end  = hscan[(bin + 1) * HB];   // bin+1==NBIN -> sentinel = NE
    cnt[t] = 0;
    __syncthreads();
    for (int e = base + t; e < end; e += 256)
        atomicAdd(&cnt[(ebuf[e] >> 16) & 255], 1);
    __syncthreads();
    int c = cnt[t];
    s[t] = c;
    __syncthreads();
    for (int o = 1; o < 256; o <<= 1) {
        int x = (t >= o) ? s[t - o] : 0;
        __syncthreads();
        s[t] += x;
        __syncthreads();
    }
    int lo = s[t] - c;                         // exclusive within bucket
    int d = (bin << 8) + t;
    if (d < NN) {
        off[d] = base + lo;
        dis[d] = rsqrtf((float)(c + 1));       // +1 self-loop
    }
    if (bin == NBIN - 1 && t == 0) off[NN] = NE;
    cur[t] = base + lo;
    __syncthreads();
    for (int e = base + t; e < end; e += 256) {
        int ed = ebuf[e];
        int p = atomicAdd(&cur[(ed >> 16) & 255], 1);
        rec[p] = (unsigned short)(ed & 0xFFFF);
    }
}

// ---------------- agg1 + gemm2 fused: one node per wave, unroll-4 -----------
__global__ __launch_bounds__(256) void k_agg1g2(const __bf16* __restrict__ H1,
                                                const float* __restrict__ dis,
                                                const float* __restrict__ b1,
                                                const __bf16* __restrict__ W2T,
                                                const int* __restrict__ off,
                                                const unsigned short* __restrict__ rec,
                                                float* __restrict__ H2) {
    const int wid = threadIdx.x >> 6, lane = threadIdx.x & 63;
    const int n = blockIdx.x * 4 + wid;
    if (n >= NN) return;
    const int g = lane >> 4, l16 = lane & 15;
    const int fo = l16 * 8;
    const float dn = dis[n];

    float a[8];
#pragma unroll
    for (int i = 0; i < 8; ++i) a[i] = 0.f;

    const int e0 = off[n], e1 = off[n + 1];
    int e = e0 + g;
    // 4 edges in flight per 16-lane group (16 rows in flight per wave)
    for (; e + 12 < e1; e += 16) {
        int r0 = rec[e];
        int r1 = rec[e + 4];
        int r2 = rec[e + 8];
        int r3 = rec[e + 12];
        float w0 = dis[r0], w1 = dis[r1], w2 = dis[r2], w3 = dis[r3];
        bf16x8 h0 = *(const bf16x8*)&H1[(size_t)r0 * DF + fo];
        bf16x8 h1 = *(const bf16x8*)&H1[(size_t)r1 * DF + fo];
        bf16x8 h2 = *(const bf16x8*)&H1[(size_t)r2 * DF + fo];
        bf16x8 h3 = *(const bf16x8*)&H1[(size_t)r3 * DF + fo];
#pragma unroll
        for (int i = 0; i < 8; ++i) a[i] += (float)h0[i] * w0;
#pragma unroll
        for (int i = 0; i < 8; ++i) a[i] += (float)h1[i] * w1;
#pragma unroll
        for (int i = 0; i < 8; ++i) a[i] += (float)h2[i] * w2;
#pragma unroll
        for (int i = 0; i < 8; ++i) a[i] += (float)h3[i] * w3;
    }
    for (; e < e1; e += 4) {
        int r = rec[e];
        float w = dis[r];
        bf16x8 h = *(const bf16x8*)&H1[(size_t)r * DF + fo];
#pragma unroll
        for (int i = 0; i < 8; ++i) a[i] += (float)h[i] * w;
    }
#pragma unroll
    for (int i = 0; i < 8; ++i) {
        a[i] += __shfl_xor(a[i], 16);
        a[i] += __shfl_xor(a[i], 32);
    }
    // finalize on ALL lanes: a = relu(edge_sum*dn + self*dn^2 + bias)
    {
        const float d2 = dn * dn;
        float4 b0 = *(const float4*)&b1[fo];
        float4 b4 = *(const float4*)&b1[fo + 4];
        bf16x8 hs = *(const bf16x8*)&H1[(size_t)n * DF + fo];
        a[0] = fmaxf(a[0] * dn + (float)hs[0] * d2 + b0.x, 0.f);
        a[1] = fmaxf(a[1] * dn + (float)hs[1] * d2 + b0.y, 0.f);
        a[2] = fmaxf(a[2] * dn + (float)hs[2] * d2 + b0.z, 0.f);
        a[3] = fmaxf(a[3] * dn + (float)hs[3] * d2 + b0.w, 0.f);
        a[4] = fmaxf(a[4] * dn + (float)hs[4] * d2 + b4.x, 0.f);
        a[5] = fmaxf(a[5] * dn + (float)hs[5] * d2 + b4.y, 0.f);
        a[6] = fmaxf(a[6] * dn + (float)hs[6] * d2 + b4.z, 0.f);
        a[7] = fmaxf(a[7] * dn + (float)hs[7] * d2 + b4.w, 0.f);
    }

    // mini-GEMM: lane computes 4 classes (g*4..g*4+3) over its 8 feats
    float p[4];
#pragma unroll
    for (int j = 0; j < 4; ++j) {
        bf16x8 wr = *(const bf16x8*)&W2T[(size_t)(g * 4 + j) * DF + fo];
        float s = 0.f;
#pragma unroll
        for (int i = 0; i < 8; ++i) s += a[i] * (float)wr[i];
        p[j] = s;
    }
#pragma unroll
    for (int o = 1; o <= 8; o <<= 1) {
#pragma unroll
        for (int j = 0; j < 4; ++j) p[j] += __shfl_xor(p[j], o);
    }
    if (l16 == 0) {
        f32x4 o4 = {p[0], p[1], p[2], p[3]};
        *(f32x4*)&H2[(size_t)n * NC + g * 4] = o4;
    }
}

// ---------------- agg layer 2: unroll-2, fused sigmoid -> OUT ---------------
__global__ __launch_bounds__(256) void k_agg2(const float* __restrict__ H2,
                                              const float* __restrict__ dis,
                                              const float* __restrict__ b2,
                                              const int* __restrict__ off,
                                              const unsigned short* __restrict__ rec,
                                              float* __restrict__ OUT) {
    const int wid = threadIdx.x >> 6, lane = threadIdx.x & 63;
    const int n = blockIdx.x * 4 + wid;
    if (n >= NN) return;
    const float dn = dis[n];

    const int g = lane >> 3, l8 = lane & 7;
    float ax = 0.f, ay = 0.f;
    const int e0 = off[n], e1 = off[n + 1];
    int e = e0 + g;
    for (; e + 8 < e1; e += 16) {
        int r0 = rec[e];
        int r1 = rec[e + 8];
        float w0 = dis[r0], w1 = dis[r1];
        float2 h0 = *(const float2*)&H2[(size_t)r0 * NC + l8 * 2];
        float2 h1 = *(const float2*)&H2[(size_t)r1 * NC + l8 * 2];
        ax += h0.x * w0;
        ay += h0.y * w0;
        ax += h1.x * w1;
        ay += h1.y * w1;
    }
    for (; e < e1; e += 8) {
        int r = rec[e];
        float w = dis[r];
        float2 h = *(const float2*)&H2[(size_t)r * NC + l8 * 2];
        ax += h.x * w;
        ay += h.y * w;
    }
    ax += __shfl_xor(ax, 8);  ay += __shfl_xor(ay, 8);
    ax += __shfl_xor(ax, 16); ay += __shfl_xor(ay, 16);
    ax += __shfl_xor(ax, 32); ay += __shfl_xor(ay, 32);
    if (g == 0) {
        float d2 = dn * dn;
        float2 hs = *(const float2*)&H2[(size_t)n * NC + l8 * 2];
        float2 bb = *(const float2*)&b2[l8 * 2];
        float vx = ax * dn + hs.x * d2 + bb.x;
        float vy = ay * dn + hs.y * d2 + bb.y;
        float2 o = { 1.0f / (1.0f + expf(-vx)), 1.0f / (1.0f + expf(-vy)) };
        *(float2*)&OUT[(size_t)n * NC + l8 * 2] = o;
    }
}

extern "C" void kernel_launch(void* const* d_in, const int* in_sizes, int n_in,
                              void* d_out, int out_size, void* d_ws, size_t ws_size,
                              hipStream_t stream) {
    const float* X  = (const float*)d_in[0];
    const int*   EI = (const int*)d_in[1];
    const float* W1 = (const float*)d_in[2];
    const float* b1 = (const float*)d_in[3];
    const float* W2 = (const float*)d_in[4];
    const float* b2 = (const float*)d_in[5];
    float* OUT = (float*)d_out;

    const int* src = EI;
    const int* dst = EI + NE;

    // workspace layout (bytes)
    char* ws = (char*)d_ws;
    int*    h       = (int*)(ws);                   // HL ints       = 306.5 KB
    int*    hscan   = (int*)(ws + 327680);          // HL+1 ints
    int*    hpart   = (int*)(ws + 655360);          // PB ints
    int*    hpartoff= (int*)(ws + 659456);          // PB ints
    int*    off     = (int*)(ws + 663552);          // NN+1 ints
    float*  dis     = (float*)(ws + 868352);        // NN floats
    __bf16* W1T     = (__bf16*)(ws + 1073152);      // 32 KB
    __bf16* W2T     = (__bf16*)(ws + 1105920);      // 4 KB
    int*    ebuf    = (int*)(ws + 1110016);         // NE int = 3.2 MB
    unsigned short* rec = (unsigned short*)(ws + 4310016);  // NE ushort = 1.6 MB
    __bf16* H1      = (__bf16*)(ws + 5910016);      // NN*DF bf16 = 12.8 MB
    float*  H2      = (float*)(ws + 18710016);      // NN*NC f32 = 3.2 MB

    const int B = 256;

    k_prep<<<(DF * DF + NC * DF + B - 1) / B, B, 0, stream>>>(W1, W2, W1T, W2T);
    k_gemm1_hist<<<GB + HB, B, 0, stream>>>(X, W1T, H1, dst, h);
    k_hpart<<<PB, B, 0, stream>>>(h, hpart);
    k_hscan_part<<<1, 512, 0, stream>>>(hpart, hpartoff, hscan);
    k_hoff<<<PB, B, 0, stream>>>(h, hpartoff, hscan);
    k_scatterA<<<HB, B, 0, stream>>>(src, dst, hscan, ebuf);
    k_rankB<<<NBIN, B, 0, stream>>>(ebuf, hscan, off, dis, rec);

    k_agg1g2<<<(NN + 3) / 4, B, 0, stream>>>(H1, dis, b1, W2T, off, rec, H2);
    k_agg2<<<(NN + 3) / 4, B, 0, stream>>>(H2, dis, b2, off, rec, OUT);
}